// Round 7
// baseline (80.181 us; speedup 1.0000x reference)
//
#include <hip/hip_runtime.h>

#define DIM   256
#define CLS   512
#define NGF   32640          // packed strict-upper-triangle floats per class
#define NQ    8160           // NGF/4 float4 quads
#define NITER 5
#define PSH   72             // y part stride in h16 (144 B -> part p banks {4p..4p+3})
#define STGF  32768          // staged floats (8192 quads, padded)

typedef _Float16 h16;
typedef __attribute__((ext_vector_type(2))) _Float16 h16x2;

__device__ __forceinline__ float dot2f(unsigned a, unsigned b, float c) {
    return __builtin_amdgcn_fdot2(__builtin_bit_cast(h16x2, a),
                                  __builtin_bit_cast(h16x2, b), c, false);
}

__device__ __forceinline__ unsigned pk2(float lo, float hi) {
#if __has_builtin(__builtin_amdgcn_cvt_pkrtz)
    return __builtin_bit_cast(unsigned, __builtin_amdgcn_cvt_pkrtz(lo, hi));
#else
    unsigned a = (unsigned)__builtin_bit_cast(unsigned short, (h16)lo);
    unsigned b = (unsigned)__builtin_bit_cast(unsigned short, (h16)hi);
    return a | (b << 16);
#endif
}

// barrier draining LDS only: async global_load_lds (vmcnt) stays in flight
__device__ __forceinline__ void bar_lds() {
    asm volatile("s_waitcnt lgkmcnt(0)\n\ts_barrier" ::: "memory");
}

__device__ __forceinline__ void gl_lds16(const float* g, float* l) {
    __builtin_amdgcn_global_load_lds(
        (const __attribute__((address_space(1))) void*)g,
        (__attribute__((address_space(3))) void*)l, 16, 0, 0);
}

__device__ __forceinline__ int cidx(int m) { return (m >> 6) * PSH + (m & 63); }

// S[r][g] gathered straight from packed upper-tri W (already staged in LDS)
__device__ __forceinline__ float gath1(const float* stg, int g, int r, int offr) {
    int lo  = ((g * (511 - g)) >> 1) + r - g - 1;   // g(511-g) is always even
    int up  = offr + g;                              // offr = off(r) - r - 1
    int idx = (g < r) ? lo : up;
    idx = idx < 0 ? 0 : idx;                         // only r==g==0 hits -1
    float v = stg[idx];
    float s = (g < r) ? -0.5f : 0.5f;
    s = (g == r) ? 0.f : s;
    return v * s;
}

#define STAGE(CC)                                                         \
    do {                                                                  \
        const float* Wc_ = W + (size_t)(CC) * NGF;                        \
        _Pragma("unroll")                                                 \
        for (int k_ = 0; k_ < 8; ++k_) {                                  \
            int chunk_ = wave * 8 + k_;             /* wave-uniform */    \
            int q_ = chunk_ * 64 + lane;                                  \
            if (q_ > NQ - 1) q_ = NQ - 1;                                 \
            gl_lds16(Wc_ + (size_t)q_ * 4, stg + chunk_ * 256);           \
        }                                                                 \
    } while (0)

#define GATHER()                                                          \
    do {                                                                  \
        const int g0_ = p << 6;                                           \
        _Pragma("unroll")                                                 \
        for (int j_ = 0; j_ < 32; ++j_) {                                 \
            float f0_ = gath1(stg, g0_ + 2 * j_,     r, offr);            \
            float f1_ = gath1(stg, g0_ + 2 * j_ + 1, r, offr);            \
            sreg[j_] = pk2(f0_, f1_);                                     \
        }                                                                 \
    } while (0)

#define ITERATE(CC)                                                       \
    do {                                                                  \
        h16* ycur_ = sy0;                                                 \
        h16* ynxt_ = sy1;                                                 \
        for (int it_ = 0; it_ < NITER; ++it_) {                           \
            const uint4* yp_ = (const uint4*)(ycur_ + p * PSH);           \
            float a0_ = 0.f, a1_ = 0.f, a2_ = 0.f, a3_ = 0.f;             \
            _Pragma("unroll")                                             \
            for (int k_ = 0; k_ < 8; ++k_) {                              \
                uint4 yv_ = yp_[k_];                                      \
                a0_ = dot2f(sreg[4 * k_ + 0], yv_.x, a0_);                \
                a1_ = dot2f(sreg[4 * k_ + 1], yv_.y, a1_);                \
                a2_ = dot2f(sreg[4 * k_ + 2], yv_.z, a2_);                \
                a3_ = dot2f(sreg[4 * k_ + 3], yv_.w, a3_);                \
            }                                                             \
            float v_ = (a0_ + a1_) + (a2_ + a3_);                         \
            v_ += __shfl_xor(v_, 1);                                      \
            v_ += __shfl_xor(v_, 2);      /* full (S y)_r on 4 lanes */   \
            if (it_ < NITER - 1) {                                        \
                if (p == 0) ynxt_[cidx(r)] = (h16)(xr - v_);              \
                h16* t_ = ycur_; ycur_ = ynxt_; ynxt_ = t_;               \
                bar_lds();                                                \
            } else {                                                      \
                if (p == 0) out[(size_t)r * CLS + (CC)] = xr - 2.f * v_;  \
            }                                                             \
        }                                                                 \
    } while (0)

__global__ void __launch_bounds__(1024)
cayley_kernel(const float* __restrict__ x, const float* __restrict__ W,
              float* __restrict__ out) {
    extern __shared__ char smem[];
    float* stg = (float*)smem;                        // 131072 B packed W
    h16*   sy0 = (h16*)(smem + STGF * 4);             // 576 B
    h16*   sy1 = sy0 + 4 * PSH;                       // 576 B

    const int tid  = threadIdx.x;
    const int r    = tid >> 2;       // row 0..255
    const int p    = tid & 3;        // part 0..3 (cols 64p..64p+63)
    const int wave = tid >> 6;
    const int lane = tid & 63;
    const int c0   = blockIdx.x;
    const int c1   = blockIdx.x + 256;
    const int offr = (r * (511 - r)) / 2 - r - 1;

    unsigned sreg[32];               // this thread's S[r][64p..64p+63] as f16x2
    float xr;

    // ===== class A =====
    STAGE(c0);
    xr = x[(size_t)r * CLS + c0];
    __syncthreads();                 // staging visible (drains vmcnt+lgkm)

    GATHER();
    if (p == 0) sy0[cidx(r)] = (h16)xr;
    __syncthreads();                 // gathers done -> stg dead; y0 visible

    STAGE(c1);                       // async prefetch: in flight during iterate A
    ITERATE(c0);

    __syncthreads();                 // drains vmcnt: class-B W staged; A reads done

    // ===== class B =====
    xr = x[(size_t)r * CLS + c1];
    GATHER();
    if (p == 0) sy0[cidx(r)] = (h16)xr;
    bar_lds();                       // y0 visible to all waves

    ITERATE(c1);
}

extern "C" void kernel_launch(void* const* d_in, const int* in_sizes, int n_in,
                              void* d_out, int out_size, void* d_ws, size_t ws_size,
                              hipStream_t stream) {
    const float* x = (const float*)d_in[0];
    const float* W = (const float*)d_in[1];
    float* out = (float*)d_out;

    const size_t smem = (size_t)STGF * 4 + 2 * 4 * PSH * 2;   // 132224 B
    hipFuncSetAttribute((const void*)cayley_kernel,
                        hipFuncAttributeMaxDynamicSharedMemorySize, (int)smem);
    hipLaunchKernelGGL(cayley_kernel, dim3(CLS / 2), dim3(1024), smem, stream, x, W, out);
}

// Round 8
// 72.035 us; speedup vs baseline: 1.1131x; 1.1131x over previous
//
#include <hip/hip_runtime.h>

#define DIM   256
#define CLS   512
#define NGF   32640          // packed strict-upper-triangle floats per class
#define NQ    8160           // NGF/4 float4 quads
#define NITER 5
#define PSH   72             // y part stride in h16 (144 B -> part p banks {4p..4p+3})
#define STGF  32768          // staged floats (8192 quads, padded)

typedef _Float16 h16;
typedef __attribute__((ext_vector_type(2))) _Float16 h16x2;

__device__ __forceinline__ float dot2f(unsigned a, unsigned b, float c) {
    return __builtin_amdgcn_fdot2(__builtin_bit_cast(h16x2, a),
                                  __builtin_bit_cast(h16x2, b), c, false);
}

__device__ __forceinline__ unsigned pk2(float lo, float hi) {
#if __has_builtin(__builtin_amdgcn_cvt_pkrtz)
    return __builtin_bit_cast(unsigned, __builtin_amdgcn_cvt_pkrtz(lo, hi));
#else
    unsigned a = (unsigned)__builtin_bit_cast(unsigned short, (h16)lo);
    unsigned b = (unsigned)__builtin_bit_cast(unsigned short, (h16)hi);
    return a | (b << 16);
#endif
}

// barrier draining LDS only: async global_load_lds (vmcnt) stays in flight
__device__ __forceinline__ void bar_lds() {
    asm volatile("s_waitcnt lgkmcnt(0)\n\ts_barrier" ::: "memory");
}

__device__ __forceinline__ void gl_lds16(const float* g, float* l) {
    __builtin_amdgcn_global_load_lds(
        (const __attribute__((address_space(1))) void*)g,
        (__attribute__((address_space(3))) void*)l, 16, 0, 0);
}

__device__ __forceinline__ int cidx(int m) { return (m >> 6) * PSH + (m & 63); }

// S[r][g] gathered straight from packed upper-tri W (already staged in LDS)
__device__ __forceinline__ float gath1(const float* stg, int g, int r, int offr) {
    int lo  = ((g * (511 - g)) >> 1) + r - g - 1;   // g(511-g) is always even
    int up  = offr + g;                              // offr = off(r) - r - 1
    int idx = (g < r) ? lo : up;
    idx = idx < 0 ? 0 : idx;                         // only r==g==0 hits -1
    float v = stg[idx];
    float s = (g < r) ? -0.5f : 0.5f;
    s = (g == r) ? 0.f : s;
    return v * s;
}

#define STAGE(CC)                                                         \
    do {                                                                  \
        const float* Wc_ = W + (size_t)(CC) * NGF;                        \
        _Pragma("unroll")                                                 \
        for (int k_ = 0; k_ < 8; ++k_) {                                  \
            int chunk_ = wave * 8 + k_;             /* wave-uniform */    \
            int q_ = chunk_ * 64 + lane;                                  \
            if (q_ > NQ - 1) q_ = NQ - 1;                                 \
            gl_lds16(Wc_ + (size_t)q_ * 4, stg + chunk_ * 256);           \
        }                                                                 \
    } while (0)

#define GATHER()                                                          \
    do {                                                                  \
        const int g0_ = p << 6;                                           \
        _Pragma("unroll")                                                 \
        for (int j_ = 0; j_ < 32; ++j_) {                                 \
            float f0_ = gath1(stg, g0_ + 2 * j_,     r, offr);            \
            float f1_ = gath1(stg, g0_ + 2 * j_ + 1, r, offr);            \
            sreg[j_] = pk2(f0_, f1_);                                     \
        }                                                                 \
    } while (0)

#define ITERATE(CC)                                                       \
    do {                                                                  \
        h16* ycur_ = sy0;                                                 \
        h16* ynxt_ = sy1;                                                 \
        for (int it_ = 0; it_ < NITER; ++it_) {                           \
            const uint4* yp_ = (const uint4*)(ycur_ + p * PSH);           \
            float a0_ = 0.f, a1_ = 0.f, a2_ = 0.f, a3_ = 0.f;             \
            _Pragma("unroll")                                             \
            for (int k_ = 0; k_ < 8; ++k_) {                              \
                uint4 yv_ = yp_[k_];                                      \
                a0_ = dot2f(sreg[4 * k_ + 0], yv_.x, a0_);                \
                a1_ = dot2f(sreg[4 * k_ + 1], yv_.y, a1_);                \
                a2_ = dot2f(sreg[4 * k_ + 2], yv_.z, a2_);                \
                a3_ = dot2f(sreg[4 * k_ + 3], yv_.w, a3_);                \
            }                                                             \
            float v_ = (a0_ + a1_) + (a2_ + a3_);                         \
            v_ += __shfl_xor(v_, 1);                                      \
            v_ += __shfl_xor(v_, 2);      /* full (S y)_r on 4 lanes */   \
            if (it_ < NITER - 1) {                                        \
                if (p == 0) ynxt_[cidx(r)] = (h16)(xr - v_);              \
                h16* t_ = ycur_; ycur_ = ynxt_; ynxt_ = t_;               \
                bar_lds();                                                \
            } else {                                                      \
                if (p == 0) out[(size_t)r * CLS + (CC)] = xr - 2.f * v_;  \
            }                                                             \
        }                                                                 \
    } while (0)

__global__ void __launch_bounds__(1024)
__attribute__((amdgpu_waves_per_eu(4, 4)))   // real occupancy is LDS-bound at 4/EU;
                                             // stop the allocator targeting 8 (VGPR 64 + spill)
cayley_kernel(const float* __restrict__ x, const float* __restrict__ W,
              float* __restrict__ out) {
    extern __shared__ char smem[];
    float* stg = (float*)smem;                        // 131072 B packed W
    h16*   sy0 = (h16*)(smem + STGF * 4);             // 576 B
    h16*   sy1 = sy0 + 4 * PSH;                       // 576 B

    const int tid  = threadIdx.x;
    const int r    = tid >> 2;       // row 0..255
    const int p    = tid & 3;        // part 0..3 (cols 64p..64p+63)
    const int wave = tid >> 6;
    const int lane = tid & 63;
    const int c0   = blockIdx.x;
    const int c1   = blockIdx.x + 256;
    const int offr = (r * (511 - r)) / 2 - r - 1;

    unsigned sreg[32];               // this thread's S[r][64p..64p+63] as f16x2
    float xr;

    // ===== class A =====
    STAGE(c0);
    xr = x[(size_t)r * CLS + c0];
    __syncthreads();                 // staging visible (drains vmcnt+lgkm)

    GATHER();
    if (p == 0) sy0[cidx(r)] = (h16)xr;
    __syncthreads();                 // gathers done -> stg dead; y0 visible

    STAGE(c1);                       // async prefetch: in flight during iterate A
    ITERATE(c0);

    __syncthreads();                 // drains vmcnt: class-B W staged; A reads done

    // ===== class B =====
    xr = x[(size_t)r * CLS + c1];
    GATHER();
    if (p == 0) sy0[cidx(r)] = (h16)xr;
    bar_lds();                       // y0 visible to all waves

    ITERATE(c1);
}

extern "C" void kernel_launch(void* const* d_in, const int* in_sizes, int n_in,
                              void* d_out, int out_size, void* d_ws, size_t ws_size,
                              hipStream_t stream) {
    const float* x = (const float*)d_in[0];
    const float* W = (const float*)d_in[1];
    float* out = (float*)d_out;

    const size_t smem = (size_t)STGF * 4 + 2 * 4 * PSH * 2;   // 132224 B
    hipFuncSetAttribute((const void*)cayley_kernel,
                        hipFuncAttributeMaxDynamicSharedMemorySize, (int)smem);
    hipLaunchKernelGGL(cayley_kernel, dim3(CLS / 2), dim3(1024), smem, stream, x, W, out);
}

// Round 9
// 46.179 us; speedup vs baseline: 1.7363x; 1.5599x over previous
//
#include <hip/hip_runtime.h>

#define DIM   256
#define CLS   512
#define NGF   32640          // packed strict-upper-triangle floats per class
#define NQ    8160           // NGF/4 float4 quads
#define NITER 5
#define PSH   72             // y part stride in h16 (144 B -> part p banks {4p..4p+3})
#define STGF  32768          // staged floats (8192 quads, padded)

typedef _Float16 h16;
typedef __attribute__((ext_vector_type(2))) _Float16 h16x2;

__device__ __forceinline__ float dot2f(unsigned a, unsigned b, float c) {
    return __builtin_amdgcn_fdot2(__builtin_bit_cast(h16x2, a),
                                  __builtin_bit_cast(h16x2, b), c, false);
}

__device__ __forceinline__ unsigned pk2(float lo, float hi) {
#if __has_builtin(__builtin_amdgcn_cvt_pkrtz)
    return __builtin_bit_cast(unsigned, __builtin_amdgcn_cvt_pkrtz(lo, hi));
#else
    unsigned a = (unsigned)__builtin_bit_cast(unsigned short, (h16)lo);
    unsigned b = (unsigned)__builtin_bit_cast(unsigned short, (h16)hi);
    return a | (b << 16);
#endif
}

// barrier draining LDS only
__device__ __forceinline__ void bar_lds() {
    asm volatile("s_waitcnt lgkmcnt(0)\n\ts_barrier" ::: "memory");
}

__device__ __forceinline__ int cidx(int m) { return (m >> 6) * PSH + (m & 63); }

// S[r][g] gathered straight from packed upper-tri W (staged in LDS)
__device__ __forceinline__ float gath1(const float* stg, int g, int r, int offr) {
    int lo  = ((g * (511 - g)) >> 1) + r - g - 1;   // g(511-g) is always even
    int up  = offr + g;                              // offr = off(r) - r - 1
    int idx = (g < r) ? lo : up;
    idx = idx < 0 ? 0 : idx;                         // only r==g==0 hits -1
    float v = stg[idx];
    float s = (g < r) ? -0.5f : 0.5f;
    s = (g == r) ? 0.f : s;
    return v * s;
}

__global__ void __launch_bounds__(1024)
cayley_kernel(const float* __restrict__ x, const float* __restrict__ W,
              float* __restrict__ out) {
    extern __shared__ char smem[];
    float*  stg  = (float*)smem;                      // 131072 B packed W
    float4* stg4 = (float4*)smem;
    h16*    sy0  = (h16*)(smem + STGF * 4);           // 576 B
    h16*    sy1  = sy0 + 4 * PSH;                     // 576 B

    const int tid  = threadIdx.x;
    const int r    = tid >> 2;       // row 0..255
    const int p    = tid & 3;        // part 0..3 (cols 64p..64p+63)
    const int c    = blockIdx.x;
    const int offr = (r * (511 - r)) / 2 - r - 1;

    unsigned sreg[32];               // this thread's S[r][64p..64p+63] as f16x2

    // ===== stage packed W into LDS: regs -> ds_write_b128 (coalesced) =====
    {
        const float4* Wc4 = (const float4*)(W + (size_t)c * NGF);
        float4 wbuf[8];
        #pragma unroll
        for (int k = 0; k < 8; ++k) {
            int q = tid + 1024 * k;
            wbuf[k] = Wc4[q < NQ ? q : 0];            // coalesced 16B/lane
        }
        #pragma unroll
        for (int k = 0; k < 8; ++k) {
            int q = tid + 1024 * k;
            if (q < NQ) stg4[q] = wbuf[k];            // lane-contiguous 1KB/wave
        }
    }
    float xr = x[(size_t)r * CLS + c];
    __syncthreads();                                  // staging visible

    // ===== gather this thread's S-row segment into registers (f16x2) =====
    {
        const int g0 = p << 6;
        #pragma unroll
        for (int j = 0; j < 32; ++j) {
            float f0 = gath1(stg, g0 + 2 * j,     r, offr);
            float f1 = gath1(stg, g0 + 2 * j + 1, r, offr);
            sreg[j] = pk2(f0, f1);
        }
    }
    if (p == 0) sy0[cidx(r)] = (h16)xr;
    __syncthreads();                                  // y0 visible

    // ===== fixed-point iteration y <- x - S y ; out = 2y - x =====
    {
        h16* ycur = sy0;
        h16* ynxt = sy1;
        for (int it = 0; it < NITER; ++it) {
            const uint4* yp = (const uint4*)(ycur + p * PSH);
            float a0 = 0.f, a1 = 0.f, a2 = 0.f, a3 = 0.f;
            #pragma unroll
            for (int k = 0; k < 8; ++k) {
                uint4 yv = yp[k];
                a0 = dot2f(sreg[4 * k + 0], yv.x, a0);
                a1 = dot2f(sreg[4 * k + 1], yv.y, a1);
                a2 = dot2f(sreg[4 * k + 2], yv.z, a2);
                a3 = dot2f(sreg[4 * k + 3], yv.w, a3);
            }
            float v = (a0 + a1) + (a2 + a3);          // partial (S y)_r
            v += __shfl_xor(v, 1);
            v += __shfl_xor(v, 2);                    // full (S y)_r on 4 lanes
            if (it < NITER - 1) {
                if (p == 0) ynxt[cidx(r)] = (h16)(xr - v);
                h16* t = ycur; ycur = ynxt; ynxt = t;
                bar_lds();
            } else {
                if (p == 0) out[(size_t)r * CLS + c] = xr - 2.f * v;
            }
        }
    }
}

extern "C" void kernel_launch(void* const* d_in, const int* in_sizes, int n_in,
                              void* d_out, int out_size, void* d_ws, size_t ws_size,
                              hipStream_t stream) {
    const float* x = (const float*)d_in[0];
    const float* W = (const float*)d_in[1];
    float* out = (float*)d_out;

    const size_t smem = (size_t)STGF * 4 + 2 * 4 * PSH * 2;   // 132224 B
    hipFuncSetAttribute((const void*)cayley_kernel,
                        hipFuncAttributeMaxDynamicSharedMemorySize, (int)smem);
    hipLaunchKernelGGL(cayley_kernel, dim3(CLS), dim3(1024), smem, stream, x, W, out);
}